// Round 1
// baseline (116.126 us; speedup 1.0000x reference)
//
#include <hip/hip_runtime.h>
#include <math.h>

// Problem constants (reference: BATCH=4096, DIM=512, sigma = s*I).
#define NB 4096
#define ND 512
#define TILE 128
#define BK 32

typedef __bf16 bf16x8 __attribute__((ext_vector_type(8)));
typedef __bf16 bf16x4 __attribute__((ext_vector_type(4)));
typedef float floatx4 __attribute__((ext_vector_type(4)));

__device__ inline void async_load16(const void* g, void* l) {
    __builtin_amdgcn_global_load_lds((const __attribute__((address_space(1))) void*)g,
                                     (__attribute__((address_space(3))) void*)l, 16, 0, 0);
}

// Kernel 1: cast mu -> bf16, compute hq[i] = 0.5 * sum(bf16(x)^2) (fp32),
// and zero sumexp (ws is re-poisoned to 0xAA before every timed launch).
__global__ __launch_bounds__(128) void prep_kernel(const float* __restrict__ mu,
                                                   __bf16* __restrict__ mubf,
                                                   float* __restrict__ hq,
                                                   float* __restrict__ sumexp) {
    const int row = blockIdx.x;
    const int t = threadIdx.x;            // 128 threads, 4 floats each = 512
    const float4 v = ((const float4*)(mu + (size_t)row * ND))[t];
    __bf16 b0 = (__bf16)v.x, b1 = (__bf16)v.y, b2 = (__bf16)v.z, b3 = (__bf16)v.w;
    bf16x4 pack; pack[0] = b0; pack[1] = b1; pack[2] = b2; pack[3] = b3;
    ((bf16x4*)(mubf + (size_t)row * ND))[t] = pack;
    float f0 = (float)b0, f1 = (float)b1, f2 = (float)b2, f3 = (float)b3;
    float sq = f0 * f0 + f1 * f1 + f2 * f2 + f3 * f3;
    #pragma unroll
    for (int off = 32; off > 0; off >>= 1) sq += __shfl_down(sq, off, 64);
    __shared__ float red[2];
    if ((t & 63) == 0) red[t >> 6] = sq;
    __syncthreads();
    if (t == 0) {
        hq[row] = 0.5f * (red[0] + red[1]);
        sumexp[row] = 0.0f;
    }
}

// Kernel 2: fused Gram (mu.mu^T via bf16 MFMA) + exp + partial row-sums.
// expo[i,j] = (G_ij - hq_i - hq_j) / s  (<= ~0 always; max is diag = 0),
// so plain sum-of-exp is safe without an online max.
__global__ __launch_bounds__(256) void gram_lse_kernel(const __bf16* __restrict__ mubf,
                                                       const float* __restrict__ hq,
                                                       const float* __restrict__ sigma,
                                                       float* __restrict__ sumexp) {
    __shared__ alignas(16) __bf16 As[TILE * BK];   // [row][k], k-stride 32
    __shared__ alignas(16) __bf16 Bs[TILE * BK];

    const int t = threadIdx.x;
    const int row0 = blockIdx.y * TILE;
    const int col0 = blockIdx.x * TILE;
    const int wave = t >> 6;
    const int lane = t & 63;
    const int r16 = lane & 15;
    const int quad = lane >> 4;
    const int rw = (wave >> 1) * 64;   // wave's row offset within tile
    const int cw = (wave & 1) * 64;    // wave's col offset within tile

    // Staging: thread t moves 16B: row srow, k-bytes [skoff*2, +16)
    const int srow = t >> 2;           // 0..63
    const int skoff = (t & 3) * 8;     // element offset in k
    const __bf16* gA0 = mubf + (size_t)(row0 + srow) * ND + skoff;
    const __bf16* gA1 = gA0 + (size_t)64 * ND;
    const __bf16* gB0 = mubf + (size_t)(col0 + srow) * ND + skoff;
    const __bf16* gB1 = gB0 + (size_t)64 * ND;
    __bf16* lA0 = &As[t * 8];
    __bf16* lA1 = &As[2048 + t * 8];
    __bf16* lB0 = &Bs[t * 8];
    __bf16* lB1 = &Bs[2048 + t * 8];

    floatx4 acc[4][4];
    #pragma unroll
    for (int i = 0; i < 4; i++)
        #pragma unroll
        for (int j = 0; j < 4; j++) {
            floatx4 z = {0.f, 0.f, 0.f, 0.f};
            acc[i][j] = z;
        }

    for (int kk = 0; kk < ND; kk += BK) {
        __syncthreads();                       // protect LDS from prior reads
        async_load16(gA0 + kk, lA0);
        async_load16(gA1 + kk, lA1);
        async_load16(gB0 + kk, lB0);
        async_load16(gB1 + kk, lB1);
        __syncthreads();                       // drains vmcnt before barrier

        bf16x8 a[4], b[4];
        #pragma unroll
        for (int i = 0; i < 4; i++)
            a[i] = *(const bf16x8*)&As[(rw + i * 16 + r16) * BK + quad * 8];
        #pragma unroll
        for (int j = 0; j < 4; j++)
            b[j] = *(const bf16x8*)&Bs[(cw + j * 16 + r16) * BK + quad * 8];
        #pragma unroll
        for (int i = 0; i < 4; i++)
            #pragma unroll
            for (int j = 0; j < 4; j++)
                acc[i][j] = __builtin_amdgcn_mfma_f32_16x16x32_bf16(a[i], b[j], acc[i][j], 0, 0, 0);
    }

    // Epilogue: C/D layout (m89-verified): col = lane&15, row = quad*4 + reg.
    const float inv_s = 1.0f / sigma[0];
    float hqc[4];
    #pragma unroll
    for (int j = 0; j < 4; j++) hqc[j] = hq[col0 + cw + j * 16 + r16];

    #pragma unroll
    for (int i = 0; i < 4; i++) {
        #pragma unroll
        for (int r = 0; r < 4; r++) {
            const int row = row0 + rw + i * 16 + quad * 4 + r;
            const float hr = hq[row];
            float rs = 0.0f;
            #pragma unroll
            for (int j = 0; j < 4; j++) {
                const float g = acc[i][j][r];
                rs += __expf((g - hr - hqc[j]) * inv_s);
            }
            // reduce over the 16 column lanes (same quad, varying lane&15)
            rs += __shfl_xor(rs, 1, 64);
            rs += __shfl_xor(rs, 2, 64);
            rs += __shfl_xor(rs, 4, 64);
            rs += __shfl_xor(rs, 8, 64);
            if (r16 == 0) atomicAdd(&sumexp[row], rs);
        }
    }
}

// Kernel 3: entropy = D/2 + ln(B) + (D/2)ln(2*pi*s) - mean_i log(sumexp_i)
__global__ __launch_bounds__(256) void finalize_kernel(const float* __restrict__ sumexp,
                                                       const float* __restrict__ sigma,
                                                       float* __restrict__ out) {
    const int t = threadIdx.x;
    float local = 0.0f;
    for (int i = t; i < NB; i += 256) local += logf(sumexp[i]);
    #pragma unroll
    for (int off = 32; off > 0; off >>= 1) local += __shfl_down(local, off, 64);
    __shared__ float red[4];
    if ((t & 63) == 0) red[t >> 6] = local;
    __syncthreads();
    if (t == 0) {
        const float tot = red[0] + red[1] + red[2] + red[3];
        const double s = (double)sigma[0];
        const double ent = (double)(ND / 2)
                         + log((double)NB)
                         + (double)(ND / 2) * log(2.0 * M_PI * s)
                         - (double)tot / (double)NB;
        out[0] = (float)ent;
        out[1] = (float)ent;
    }
}

extern "C" void kernel_launch(void* const* d_in, const int* in_sizes, int n_in,
                              void* d_out, int out_size, void* d_ws, size_t ws_size,
                              hipStream_t stream) {
    (void)in_sizes; (void)n_in; (void)out_size; (void)ws_size;
    const float* codewords = (const float*)d_in[1];  // d_in[0] = info (unused)
    const float* sigma     = (const float*)d_in[2];
    float* out = (float*)d_out;

    char* ws = (char*)d_ws;
    __bf16* mubf  = (__bf16*)ws;                                  // 4 MB
    float*  hq    = (float*)(ws + (size_t)NB * ND * 2);           // 16 KB
    float*  sumexp = hq + NB;                                     // 16 KB

    prep_kernel<<<NB, 128, 0, stream>>>(codewords, mubf, hq, sumexp);
    dim3 grid(NB / TILE, NB / TILE);   // 32 x 32 tiles
    gram_lse_kernel<<<grid, 256, 0, stream>>>(mubf, hq, sigma, sumexp);
    finalize_kernel<<<1, 256, 0, stream>>>(sumexp, sigma, out);
}